// Round 11
// baseline (228.804 us; speedup 1.0000x reference)
//
#include <hip/hip_runtime.h>
#include <hip/hip_bf16.h>

// GCN: 2x GCNConv(128->128) + LeakyReLU(0.1) + mean over channels.
// N=50000, E=1600000, D=128, fp32 in/out.
//
// R11: quartered gather v2. R8 proved XCD-pinned channel-quarters collapse
//     gather FETCH to the compulsory floor (23.5MB measured); it lost on 4x
//     wave count (200K waves x ~2 iters = overhead-bound 104us). v2 keeps
//     R10's 50K waves: one wave = 4 (node,quarter) tasks, 16 lanes/node
//     (4 chains x 4 lanes x uint4 = one 64B line/edge). q=(blockIdx&7)>>1 ->
//     each XCD gathers from ONE 3.2MB quarter table (fits 4MB L2). g stays
//     UNSCALED (keeps K4 sort||gemm fusion); dinv[src] folded into the fma.
//     R10 gather: 56us, FETCH 150MB @2.77TB/s, VALU 48% (half fetch-bound).
// Math (verified R2-R10): h[u]=bf16((x@W1)[u]);
//   mg[u]=dinv[u]*dot(lrelu(dinv[u]*sum_{n in N(u)+u} dinv[n]*h[n] + b1), mean_j W2[:,j]);
//   out[v]=dinv[v]*(mg[v]+sum mg[nbr]) + mean(b2).

#define N_NODES 50000
#define NPAD 50048
#define D 128
#define BK 196           // node buckets: v>>8
#define CHUNK 4096       // edges per stage-1 block

typedef unsigned int uint;
typedef unsigned short u16;
typedef __attribute__((ext_vector_type(8))) short short8;   // 8 bf16 (4 VGPRs)
typedef __attribute__((ext_vector_type(4))) float floatx4;

__device__ __forceinline__ u16 cvt_bf16(float f) {
    uint u = __float_as_uint(f);
    return (u16)((u + 0x7fffu + ((u >> 16) & 1u)) >> 16);   // RNE
}
__device__ __forceinline__ uint pack_bf2(float a, float b) {
    return (uint)cvt_bf16(a) | ((uint)cvt_bf16(b) << 16);
}

// ---------------- K1: per-chunk bucket histogram  +  w2m  +  counter init ----------------
__global__ void hist_w2m_kernel(const int* __restrict__ dst, uint* __restrict__ H,
                                const float* __restrict__ W2, const float* __restrict__ b2,
                                float* __restrict__ w2m, uint* __restrict__ counter,
                                int E, int CHN) {
    int t = threadIdx.x, c = blockIdx.x;
    if (c < CHN) {                         // histogram chunk
        __shared__ uint h[BK];
        if (t < BK) h[t] = 0;
        __syncthreads();
        int e0 = c * CHUNK;
        for (int i = t; i < CHUNK; i += 256) {
            int e = e0 + i;
            if (e < E) atomicAdd(&h[dst[e] >> 8], 1u);
        }
        __syncthreads();
        if (t < BK) H[t * CHN + c] = h[t]; // bucket-major for column scan
    } else {                               // w2m block
        if (t < 128) {
            float s = 0.f;
            for (int j = 0; j < 128; j++) s += W2[t * 128 + j];
            w2m[t] = s * (1.0f / 128.0f);
        } else if (t == 128) {
            float s = 0.f;
            for (int j = 0; j < 128; j++) s += b2[j];
            w2m[128] = s * (1.0f / 128.0f);
        } else if (t == 129) {
            *counter = 0;                  // for K2 last-block detection
        }
    }
}

// ---------------- K2: per-bucket scan over chunks; last block scans totals ----------------
__global__ void scan_kernel(uint* __restrict__ H, uint* __restrict__ T, uint* __restrict__ B,
                            int* __restrict__ row, uint* __restrict__ counter,
                            int CHN, int E, int N) {
    __shared__ uint s[256];
    __shared__ uint ticket_sh;
    int t = threadIdx.x, b = blockIdx.x;
    uint carry = 0;
    for (int base = 0; base < CHN; base += 256) {
        int idx = base + t;
        uint v = (idx < CHN) ? H[b * CHN + idx] : 0u;
        s[t] = v;
        __syncthreads();
#pragma unroll
        for (int off = 1; off < 256; off <<= 1) {
            uint u = (t >= off) ? s[t - off] : 0u;
            __syncthreads();
            s[t] += u;
            __syncthreads();
        }
        if (idx < CHN) H[b * CHN + idx] = carry + s[t] - v;   // exclusive + carry
        carry += s[255];
        __syncthreads();
    }
    if (t == 0) {
        atomicExch(&T[b], carry);          // device-scope store (crosses XCD L2s)
        __threadfence();
        ticket_sh = atomicAdd(counter, 1);
    }
    __syncthreads();
    if (ticket_sh == (uint)(gridDim.x - 1)) {      // last block: scan bucket totals
        __threadfence();
        uint v = (t < BK) ? atomicAdd(&T[t], 0u) : 0u;   // atomic read (coherent)
        s[t] = v;
        __syncthreads();
#pragma unroll
        for (int off = 1; off < 256; off <<= 1) {
            uint u = (t >= off) ? s[t - off] : 0u;
            __syncthreads();
            s[t] += u;
            __syncthreads();
        }
        if (t < BK) B[t] = s[t] - v;
        if (t == 0) { B[BK] = (uint)E; row[N] = E; }
    }
}

// ---------------- K3: scatter edges into bucket regions (LDS cursors) ----------------
__global__ void scatter_kernel(const int* __restrict__ src, const int* __restrict__ dst,
                               const uint* __restrict__ H, const uint* __restrict__ B,
                               uint* __restrict__ EB, int E, int CHN) {
    __shared__ uint cur[BK];
    int t = threadIdx.x, c = blockIdx.x;
    if (t < BK) cur[t] = B[t] + H[t * CHN + c];
    __syncthreads();
    int e0 = c * CHUNK;
    for (int i = t; i < CHUNK; i += 256) {
        int e = e0 + i;
        if (e < E) {
            int d = dst[e];
            uint slot = atomicAdd(&cur[d >> 8], 1u);
            EB[slot] = ((uint)(d & 255) << 16) | (uint)src[e];
        }
    }
}

// ---------------- K4: bucket_sort (blocks 0..BK-1)  ||  MFMA gemm (blocks BK..) ----------------
// Sort: per-bucket counting sort by dst&255 -> esrc, row, dinv (dense writes).
// Gemm: quarter-major g16 = bf16( x @ W1 ) -- UNSCALED (dinv applied per-edge),
//       so gemm has no dependence on sort outputs; safe to run concurrently.
//       channel c of row r -> uint index (c>>5)*NPAD*16 + r*16 + ((c&31)>>1).
#define WT_STRIDE 136
union SortGemmSmem {
    struct { uint cnt[256], s[256], cur[256]; } sort;
    u16 wt[128 * WT_STRIDE];               // 34.8 KB
};
__global__ __launch_bounds__(256) void sortgemm_kernel(
    const uint* __restrict__ EB, const uint* __restrict__ B,
    int* __restrict__ row, float* __restrict__ dinv, u16* __restrict__ esrc,
    const float* __restrict__ A, const float* __restrict__ W,
    uint* __restrict__ G32, int N, int M) {
    __shared__ SortGemmSmem sm;
    int t = threadIdx.x;

    if (blockIdx.x < BK) {                 // ---- bucket sort ----
        int b = blockIdx.x;
        uint base = B[b], ne = B[b + 1] - base;
        sm.sort.cnt[t] = 0;
        __syncthreads();
        for (uint i = t; i < ne; i += 256) atomicAdd(&sm.sort.cnt[EB[base + i] >> 16], 1u);
        __syncthreads();
        uint c = sm.sort.cnt[t];
        sm.sort.s[t] = c;
        __syncthreads();
#pragma unroll
        for (int off = 1; off < 256; off <<= 1) {
            uint u = (t >= off) ? sm.sort.s[t - off] : 0u;
            __syncthreads();
            sm.sort.s[t] += u;
            __syncthreads();
        }
        uint p = sm.sort.s[t] - c;          // exclusive prefix within bucket
        int v = (b << 8) + t;
        if (v < N) {
            row[v] = (int)(base + p);
            dinv[v] = rsqrtf((float)(c + 1u));   // +1 self-loop
        }
        sm.sort.cur[t] = base + p;
        __syncthreads();
        for (uint i = t; i < ne; i += 256) {
            uint u = EB[base + i];
            uint slot = atomicAdd(&sm.sort.cur[u >> 16], 1u);
            esrc[slot] = (u16)(u & 0xffffu);
        }
    } else {                               // ---- MFMA gemm ----
        int bid = blockIdx.x - BK;
        for (int i = t; i < 128 * 128; i += 256) {   // stage W1^T as bf16
            int k = i >> 7, n = i & 127;
            sm.wt[n * WT_STRIDE + k] = cvt_bf16(W[i]);
        }
        __syncthreads();

        int wave = t >> 6, lane = t & 63;
        int m = lane & 15, quad = lane >> 4;
        int rowa = bid * 64 + wave * 16 + m;
        int rowc = rowa < M ? rowa : M - 1;
        const float* Arow = A + (long)rowc * D;

        short8 afrag[4];
#pragma unroll
        for (int kt = 0; kt < 4; kt++) {
            int k0 = kt * 32 + quad * 8;
            float4 f0 = *(const float4*)(Arow + k0);
            float4 f1 = *(const float4*)(Arow + k0 + 4);
            short8 af;
            af[0] = (short)cvt_bf16(f0.x); af[1] = (short)cvt_bf16(f0.y);
            af[2] = (short)cvt_bf16(f0.z); af[3] = (short)cvt_bf16(f0.w);
            af[4] = (short)cvt_bf16(f1.x); af[5] = (short)cvt_bf16(f1.y);
            af[6] = (short)cvt_bf16(f1.z); af[7] = (short)cvt_bf16(f1.w);
            afrag[kt] = af;
        }

        int orow0 = bid * 64 + wave * 16;
        for (int n0 = 0; n0 < 128; n0 += 16) {
            floatx4 acc = {0.f, 0.f, 0.f, 0.f};
#pragma unroll
            for (int kt = 0; kt < 4; kt++) {
                short8 bf = *(const short8*)(sm.wt + (n0 + m) * WT_STRIDE + kt * 32 + quad * 8);
                acc = __builtin_amdgcn_mfma_f32_16x16x32_bf16(afrag[kt], bf, acc, 0, 0, 0);
            }
#pragma unroll
            for (int r = 0; r < 4; r++) {
                float val = acc[r];
                float oth = __shfl_xor(val, 1, 64);      // partner column
                int orow = orow0 + quad * 4 + r;
                if (orow < M && (m & 1) == 0) {
                    int c = n0 + m;
                    G32[(long)(c >> 5) * NPAD * 16 + (long)orow * 16 + ((c & 31) >> 1)]
                        = pack_bf2(val, oth);
                }
            }
        }
    }
}

// ---------------- K5: quartered gather v2 ----------------
// One wave = 4 (node,quarter) tasks, same quarter. 16 lanes/node: 4 chains x
// 4 lanes x uint4 (one 64B quarter-row per edge). q=(blockIdx&7)>>1 pins each
// XCD to one 3.2MB quarter table. dinv[src] applied via fma (g unscaled).
__global__ __launch_bounds__(256) void gather_q2_kernel(
    const int* __restrict__ row, const u16* __restrict__ esrc,
    const uint* __restrict__ g16, const float* __restrict__ dinv,
    const float* __restrict__ b1, const float* __restrict__ w2m,
    float* __restrict__ partial, int N) {
    int b = blockIdx.x;
    int slot = b & 7;
    int q = slot >> 1;
    int wave = threadIdx.x >> 6;
    int lane = threadIdx.x & 63;
    int grp = lane >> 4;           // node within wave (4 per wave)
    int g = lane & 15;
    int chain = g >> 2, p = g & 3; // 4 chains x 4 lanes (uint4 each)
    int v = (b >> 3) * 32 + (slot & 1) * 16 + wave * 4 + grp;
    if (v >= N) return;

    const uint4* gq = (const uint4*)(g16 + (long)q * NPAD * 16);  // 4 uint4/row
    float dvv = dinv[v];
    float acc[8];
#pragma unroll
    for (int i = 0; i < 8; i++) acc[i] = 0.f;

#define ACC4(u, wgt) {                                                   \
    acc[0] += (wgt) * __uint_as_float((u).x << 16);                      \
    acc[1] += (wgt) * __uint_as_float((u).x & 0xffff0000u);              \
    acc[2] += (wgt) * __uint_as_float((u).y << 16);                      \
    acc[3] += (wgt) * __uint_as_float((u).y & 0xffff0000u);              \
    acc[4] += (wgt) * __uint_as_float((u).z << 16);                      \
    acc[5] += (wgt) * __uint_as_float((u).z & 0xffff0000u);              \
    acc[6] += (wgt) * __uint_as_float((u).w << 16);                      \
    acc[7] += (wgt) * __uint_as_float((u).w & 0xffff0000u); }

    if (chain == 0) {              // self-loop term: dinv[v]*h[v]
        uint4 u = gq[(long)v * 4 + p];
        ACC4(u, dvv)
    }
    int jb = (int)__builtin_nontemporal_load(&row[v]);
    int je = (int)__builtin_nontemporal_load(&row[v + 1]);
    int j = jb + chain;
    if (j < je) {                  // 2-deep pipeline per chain
        int s0 = (int)__builtin_nontemporal_load(&esrc[j]);
        float w0 = dinv[s0];
        uint4 u0 = gq[(long)s0 * 4 + p];
        j += 4;
        while (j < je) {
            int s1 = (int)__builtin_nontemporal_load(&esrc[j]);
            float w1 = dinv[s1];
            uint4 u1 = gq[(long)s1 * 4 + p];
            j += 4;
            ACC4(u0, w0)
            u0 = u1; w0 = w1;
        }
        ACC4(u0, w0)
    }
#undef ACC4

    // butterfly over the 4 chains (xor 4, 8 stay inside the 16-lane group)
#pragma unroll
    for (int i = 0; i < 8; i++) {
        acc[i] += __shfl_xor(acc[i], 4, 64);
        acc[i] += __shfl_xor(acc[i], 8, 64);
    }

    // epilogue on all 16 lanes (p-dependent): lane p holds channels q*32+8p..+7
    const float2* bp = (const float2*)b1;
    const float2* wp = (const float2*)w2m;
    float s = 0.f;
#pragma unroll
    for (int k = 0; k < 4; k++) {
        float2 bb = bp[q * 16 + p * 4 + k];
        float2 wm = wp[q * 16 + p * 4 + k];
        float t0 = dvv * acc[2 * k]     + bb.x; t0 = t0 >= 0.f ? t0 : 0.1f * t0;
        float t1 = dvv * acc[2 * k + 1] + bb.y; t1 = t1 >= 0.f ? t1 : 0.1f * t1;
        s += t0 * wm.x + t1 * wm.y;
    }
    s += __shfl_xor(s, 1, 64);
    s += __shfl_xor(s, 2, 64);
    if (g == 0) partial[q * NPAD + v] = s;
}

// ---------------- K5b: mg[v] = dinv[v] * sum_q partial[q][v] ----------------
__global__ void mg_kernel(const float* __restrict__ partial, const float* __restrict__ dinv,
                          float* __restrict__ mg, int N) {
    int v = blockIdx.x * blockDim.x + threadIdx.x;
    if (v >= N) return;
    mg[v] = dinv[v] * (partial[v] + partial[NPAD + v] +
                       partial[2 * NPAD + v] + partial[3 * NPAD + v]);
}

// ---------------- K6: scalar aggregate for conv2 + mean ----------------
__global__ void out_kernel(const int* __restrict__ row, const u16* __restrict__ esrc,
                           const float* __restrict__ mg, const float* __restrict__ dinv,
                           const float* __restrict__ w2m, float* __restrict__ out, int N) {
    int v = blockIdx.x * blockDim.x + threadIdx.x;
    if (v >= N) return;
    float acc = mg[v];
    int jb = row[v], je = row[v + 1];
    int j = jb;
    for (; j + 8 <= je; j += 8) {
        acc += mg[esrc[j]] + mg[esrc[j + 1]] + mg[esrc[j + 2]] + mg[esrc[j + 3]] +
               mg[esrc[j + 4]] + mg[esrc[j + 5]] + mg[esrc[j + 6]] + mg[esrc[j + 7]];
    }
    for (; j < je; j++) acc += mg[esrc[j]];
    out[v] = dinv[v] * acc + w2m[128];
}

extern "C" void kernel_launch(void* const* d_in, const int* in_sizes, int n_in,
                              void* d_out, int out_size, void* d_ws, size_t ws_size,
                              hipStream_t stream) {
    const float* x  = (const float*)d_in[0];
    const int* ei   = (const int*)d_in[1];
    const float* W1 = (const float*)d_in[2];
    const float* b1 = (const float*)d_in[3];
    const float* W2 = (const float*)d_in[4];
    const float* b2 = (const float*)d_in[5];
    float* out = (float*)d_out;

    const int N = N_NODES;
    const int E = in_sizes[1] / 2;
    const int* src = ei;
    const int* dst = ei + E;
    const int CHN = (E + CHUNK - 1) / CHUNK;   // 391
    const int nblocks = (N + 255) / 256;       // 196

    // workspace (4B units). EB is NOT aliased with g16 (sort runs || gemm in K4).
    float*    dinv    = (float*)d_ws;                     // [NPAD]
    int*      row     = (int*)(dinv + NPAD);              // [NPAD+16]
    uint*     B       = (uint*)(row + NPAD + 16);         // [256] (BK+1 used)
    float*    w2m     = (float*)(B + 256);                // [256] ([128]=mean b2)
    float*    mg      = w2m + 256;                        // [NPAD]
    uint*     T       = (uint*)(mg + NPAD);               // [256]
    uint*     counter = T + 256;                          // [16]
    float*    partial = (float*)(counter + 16);           // [4*NPAD]
    uint*     g16u    = (uint*)(partial + 4 * NPAD);      // [NPAD*64] quarter-major
    u16*      esrc    = (u16*)(g16u + (long)NPAD * 64);   // [E] u16
    uint*     H       = (uint*)(esrc + E);                // [BK*CHN]
    uint*     EB      = H + BK * CHN;                     // [E]

    // K1: histogram chunks + w2m + counter init
    hist_w2m_kernel<<<CHN + 1, 256, 0, stream>>>(dst, H, W2, b2, w2m, counter, E, CHN);
    // K2: per-bucket chunk scan; last block produces B[] and row[N]
    scan_kernel<<<BK, 256, 0, stream>>>(H, T, B, row, counter, CHN, E, N);
    // K3: scatter into bucket regions
    scatter_kernel<<<CHN, 256, 0, stream>>>(src, dst, H, B, EB, E, CHN);
    // K4: bucket sort (196 blocks) || MFMA gemm quarter-major (782 blocks)
    sortgemm_kernel<<<BK + (N + 63) / 64, 256, 0, stream>>>(EB, B, row, dinv, esrc,
                                                            x, W1, g16u, N, N);
    // K5: XCD-pinned quartered gather -> partial[q][v]
    gather_q2_kernel<<<((N + 31) / 32) * 8, 256, 0, stream>>>(row, esrc, g16u, dinv,
                                                              b1, w2m, partial, N);
    // K5b: mg combine
    mg_kernel<<<nblocks, 256, 0, stream>>>(partial, dinv, mg, N);
    // K6: scalar aggregate + mean -> out
    out_kernel<<<nblocks, 256, 0, stream>>>(row, esrc, mg, dinv, w2m, out, N);
}

// Round 12
// 197.924 us; speedup vs baseline: 1.1560x; 1.1560x over previous
//
#include <hip/hip_runtime.h>
#include <hip/hip_bf16.h>

// GCN: 2x GCNConv(128->128) + LeakyReLU(0.1) + mean over channels.
// N=50000, E=1600000, D=128, fp32 in/out.
//
// R12 = R10 (best: 196us) + parallel w2m. R11's quartered gather v2 hit the
//     compulsory FETCH floor (23.5MB, XCD pinning verified 3x) but regressed
//     to 80us (latency/structure-bound at VALU 28%) -> shelved; full-row
//     gather (56us, fetch-bound 150MB @2.77TB/s) restored.
//     Hidden-cost fix: R9-R11 computed w2m in ONE block with 128 serial
//     stride-512B column sums on a single CU (est. 20-40us, invisible in
//     top-5 because gather fills all 5 slots). Now: 33 extra K1 blocks, one
//     wave per k, coalesced 64-lane read + shfl reduce (R7 layout, <5us).
// Math (verified R2-R11): h[u]=bf16((x@W1)[u]);
//   mg[u]=dinv[u]*dot(lrelu(dinv[u]*sum_{n in N(u)+u} dinv[n]*h[n] + b1), mean_j W2[:,j]);
//   out[v]=dinv[v]*(mg[v]+sum mg[nbr]) + mean(b2).

#define N_NODES 50000
#define NPAD 50048
#define D 128
#define BK 196           // node buckets: v>>8
#define CHUNK 4096       // edges per stage-1 block

typedef unsigned int uint;
typedef unsigned short u16;
typedef __attribute__((ext_vector_type(8))) short short8;   // 8 bf16 (4 VGPRs)
typedef __attribute__((ext_vector_type(4))) float floatx4;

__device__ __forceinline__ u16 cvt_bf16(float f) {
    uint u = __float_as_uint(f);
    return (u16)((u + 0x7fffu + ((u >> 16) & 1u)) >> 16);   // RNE
}
__device__ __forceinline__ uint pack_bf2(float a, float b) {
    return (uint)cvt_bf16(a) | ((uint)cvt_bf16(b) << 16);
}

// ---------------- K1: per-chunk bucket histogram  +  parallel w2m  +  counter init ----------------
__global__ void hist_w2m_kernel(const int* __restrict__ dst, uint* __restrict__ H,
                                const float* __restrict__ W2, const float* __restrict__ b2,
                                float* __restrict__ w2m, uint* __restrict__ counter,
                                int E, int CHN) {
    int t = threadIdx.x, c = blockIdx.x;
    if (c < CHN) {                         // histogram chunk
        __shared__ uint h[BK];
        if (t < BK) h[t] = 0;
        __syncthreads();
        int e0 = c * CHUNK;
        for (int i = t; i < CHUNK; i += 256) {
            int e = e0 + i;
            if (e < E) atomicAdd(&h[dst[e] >> 8], 1u);
        }
        __syncthreads();
        if (t < BK) H[t * CHN + c] = h[t]; // bucket-major for column scan
    } else {                               // w2m waves: one wave per output k
        int wave = t >> 6, lane = t & 63;
        int k = (c - CHN) * 4 + wave;      // 33 blocks x 4 waves = 132 >= 130
        if (k < 128) {                     // w2m[k] = mean_j W2[k][j], coalesced
            float s = W2[k * 128 + lane] + W2[k * 128 + 64 + lane];
#pragma unroll
            for (int off = 32; off > 0; off >>= 1) s += __shfl_down(s, off, 64);
            if (lane == 0) w2m[k] = s * (1.0f / 128.0f);
        } else if (k == 128) {             // mean(b2)
            float s = b2[lane] + b2[lane + 64];
#pragma unroll
            for (int off = 32; off > 0; off >>= 1) s += __shfl_down(s, off, 64);
            if (lane == 0) w2m[128] = s * (1.0f / 128.0f);
        } else if (k == 129) {
            if (lane == 0) *counter = 0;   // for K2 last-block detection
        }
    }
}

// ---------------- K2: per-bucket scan over chunks; last block scans totals ----------------
__global__ void scan_kernel(uint* __restrict__ H, uint* __restrict__ T, uint* __restrict__ B,
                            int* __restrict__ row, uint* __restrict__ counter,
                            int CHN, int E, int N) {
    __shared__ uint s[256];
    __shared__ uint ticket_sh;
    int t = threadIdx.x, b = blockIdx.x;
    uint carry = 0;
    for (int base = 0; base < CHN; base += 256) {
        int idx = base + t;
        uint v = (idx < CHN) ? H[b * CHN + idx] : 0u;
        s[t] = v;
        __syncthreads();
#pragma unroll
        for (int off = 1; off < 256; off <<= 1) {
            uint u = (t >= off) ? s[t - off] : 0u;
            __syncthreads();
            s[t] += u;
            __syncthreads();
        }
        if (idx < CHN) H[b * CHN + idx] = carry + s[t] - v;   // exclusive + carry
        carry += s[255];
        __syncthreads();
    }
    if (t == 0) {
        atomicExch(&T[b], carry);          // device-scope store (crosses XCD L2s)
        __threadfence();
        ticket_sh = atomicAdd(counter, 1);
    }
    __syncthreads();
    if (ticket_sh == (uint)(gridDim.x - 1)) {      // last block: scan bucket totals
        __threadfence();
        uint v = (t < BK) ? atomicAdd(&T[t], 0u) : 0u;   // atomic read (coherent)
        s[t] = v;
        __syncthreads();
#pragma unroll
        for (int off = 1; off < 256; off <<= 1) {
            uint u = (t >= off) ? s[t - off] : 0u;
            __syncthreads();
            s[t] += u;
            __syncthreads();
        }
        if (t < BK) B[t] = s[t] - v;
        if (t == 0) { B[BK] = (uint)E; row[N] = E; }
    }
}

// ---------------- K3: scatter edges into bucket regions (LDS cursors) ----------------
__global__ void scatter_kernel(const int* __restrict__ src, const int* __restrict__ dst,
                               const uint* __restrict__ H, const uint* __restrict__ B,
                               uint* __restrict__ EB, int E, int CHN) {
    __shared__ uint cur[BK];
    int t = threadIdx.x, c = blockIdx.x;
    if (t < BK) cur[t] = B[t] + H[t * CHN + c];
    __syncthreads();
    int e0 = c * CHUNK;
    for (int i = t; i < CHUNK; i += 256) {
        int e = e0 + i;
        if (e < E) {
            int d = dst[e];
            uint slot = atomicAdd(&cur[d >> 8], 1u);
            EB[slot] = ((uint)(d & 255) << 16) | (uint)src[e];
        }
    }
}

// ---------------- K4: bucket_sort (blocks 0..BK-1)  ||  MFMA gemm (blocks BK..) ----------------
// Sort: per-bucket counting sort by dst&255 -> esrc, row, dinv (dense writes).
// Gemm: g16[M,128] = bf16( x @ W1 )  -- UNSCALED (dinv applied per-edge in gather),
//       so gemm has no dependence on sort outputs; safe to run concurrently.
#define WT_STRIDE 136
union SortGemmSmem {
    struct { uint cnt[256], s[256], cur[256]; } sort;
    u16 wt[128 * WT_STRIDE];               // 34.8 KB
};
__global__ __launch_bounds__(256) void sortgemm_kernel(
    const uint* __restrict__ EB, const uint* __restrict__ B,
    int* __restrict__ row, float* __restrict__ dinv, u16* __restrict__ esrc,
    const float* __restrict__ A, const float* __restrict__ W,
    uint* __restrict__ G32, int N, int M) {
    __shared__ SortGemmSmem sm;
    int t = threadIdx.x;

    if (blockIdx.x < BK) {                 // ---- bucket sort ----
        int b = blockIdx.x;
        uint base = B[b], ne = B[b + 1] - base;
        sm.sort.cnt[t] = 0;
        __syncthreads();
        for (uint i = t; i < ne; i += 256) atomicAdd(&sm.sort.cnt[EB[base + i] >> 16], 1u);
        __syncthreads();
        uint c = sm.sort.cnt[t];
        sm.sort.s[t] = c;
        __syncthreads();
#pragma unroll
        for (int off = 1; off < 256; off <<= 1) {
            uint u = (t >= off) ? sm.sort.s[t - off] : 0u;
            __syncthreads();
            sm.sort.s[t] += u;
            __syncthreads();
        }
        uint p = sm.sort.s[t] - c;          // exclusive prefix within bucket
        int v = (b << 8) + t;
        if (v < N) {
            row[v] = (int)(base + p);
            dinv[v] = rsqrtf((float)(c + 1u));   // +1 self-loop
        }
        sm.sort.cur[t] = base + p;
        __syncthreads();
        for (uint i = t; i < ne; i += 256) {
            uint u = EB[base + i];
            uint slot = atomicAdd(&sm.sort.cur[u >> 16], 1u);
            esrc[slot] = (u16)(u & 0xffffu);
        }
    } else {                               // ---- MFMA gemm ----
        int bid = blockIdx.x - BK;
        for (int i = t; i < 128 * 128; i += 256) {   // stage W1^T as bf16
            int k = i >> 7, n = i & 127;
            sm.wt[n * WT_STRIDE + k] = cvt_bf16(W[i]);
        }
        __syncthreads();

        int wave = t >> 6, lane = t & 63;
        int m = lane & 15, quad = lane >> 4;
        int rowa = bid * 64 + wave * 16 + m;
        int rowc = rowa < M ? rowa : M - 1;
        const float* Arow = A + (long)rowc * D;

        short8 afrag[4];
#pragma unroll
        for (int kt = 0; kt < 4; kt++) {
            int k0 = kt * 32 + quad * 8;
            float4 f0 = *(const float4*)(Arow + k0);
            float4 f1 = *(const float4*)(Arow + k0 + 4);
            short8 af;
            af[0] = (short)cvt_bf16(f0.x); af[1] = (short)cvt_bf16(f0.y);
            af[2] = (short)cvt_bf16(f0.z); af[3] = (short)cvt_bf16(f0.w);
            af[4] = (short)cvt_bf16(f1.x); af[5] = (short)cvt_bf16(f1.y);
            af[6] = (short)cvt_bf16(f1.z); af[7] = (short)cvt_bf16(f1.w);
            afrag[kt] = af;
        }

        int orow0 = bid * 64 + wave * 16;
        for (int n0 = 0; n0 < 128; n0 += 16) {
            floatx4 acc = {0.f, 0.f, 0.f, 0.f};
#pragma unroll
            for (int kt = 0; kt < 4; kt++) {
                short8 bf = *(const short8*)(sm.wt + (n0 + m) * WT_STRIDE + kt * 32 + quad * 8);
                acc = __builtin_amdgcn_mfma_f32_16x16x32_bf16(afrag[kt], bf, acc, 0, 0, 0);
            }
#pragma unroll
            for (int r = 0; r < 4; r++) {
                float val = acc[r];
                float oth = __shfl_xor(val, 1, 64);      // partner column
                int orow = orow0 + quad * 4 + r;
                if (orow < M && (m & 1) == 0)
                    G32[(long)orow * 64 + ((n0 + m) >> 1)] = pack_bf2(val, oth);
            }
        }
    }
}

// ---------------- K5: fused gather(bf16, dinv-fma) + leakyrelu + dot(w2m) ----------------
// One wave/node; 8 chains x 8 lanes; 2 uint4/edge, 2-deep pipeline.
// dinv[src] applied per edge via fma (g is unscaled).
__global__ __launch_bounds__(256) void gather_node_kernel(
    const int* __restrict__ row, const u16* __restrict__ esrc,
    const uint* __restrict__ g16, const float* __restrict__ dinv,
    const float* __restrict__ b1, const float* __restrict__ w2m,
    float* __restrict__ mg, int N) {
    int wave = threadIdx.x >> 6;
    int lane = threadIdx.x & 63;
    int sub = lane & 7;        // 16-channel slice: uint4 pair 2*sub, 2*sub+1
    int nb = lane >> 3;        // 8 neighbor chains
    int v = blockIdx.x * 4 + wave;
    if (v >= N) return;

    const uint4* gv = (const uint4*)g16;   // 16 uint4 per 256B row
    float dvv = dinv[v];
    float acc[16];
#pragma unroll
    for (int i = 0; i < 16; i++) acc[i] = 0.f;

#define ACC8(ua, ub, wgt) {                                              \
    uint uu[8] = {(ua).x, (ua).y, (ua).z, (ua).w, (ub).x, (ub).y, (ub).z, (ub).w}; \
    _Pragma("unroll")                                                    \
    for (int i = 0; i < 8; i++) {                                        \
        acc[2*i]   += (wgt) * __uint_as_float(uu[i] << 16);              \
        acc[2*i+1] += (wgt) * __uint_as_float(uu[i] & 0xffff0000u);      \
    } }

    if (nb == 0) {             // self-loop term: dinv[v]*h[v]
        long rb = (long)v * 16 + 2 * sub;
        uint4 ua = gv[rb], ub = gv[rb + 1];
        ACC8(ua, ub, dvv)
    }
    int jb = row[v], je = row[v + 1];
    int j = jb + nb;
    if (j < je) {              // 2-deep pipeline per chain
        int s0 = esrc[j];
        float wA = dinv[s0];
        long r0 = (long)s0 * 16 + 2 * sub;
        uint4 p0 = gv[r0], p1 = gv[r0 + 1];
        j += 8;
        while (j < je) {
            int s1 = esrc[j];
            float wB = dinv[s1];
            long r1 = (long)s1 * 16 + 2 * sub;
            uint4 q0 = gv[r1], q1 = gv[r1 + 1];
            j += 8;
            ACC8(p0, p1, wA)
            p0 = q0; p1 = q1; wA = wB;
        }
        ACC8(p0, p1, wA)
    }
#undef ACC8

    // reduce the 8 chains
#pragma unroll
    for (int i = 0; i < 16; i++) {
        acc[i] += __shfl_xor(acc[i], 8, 64);
        acc[i] += __shfl_xor(acc[i], 16, 64);
        acc[i] += __shfl_xor(acc[i], 32, 64);
    }

    if (nb == 0) {             // lane sub holds channels 16*sub .. 16*sub+15
        const float4* bp = (const float4*)b1;
        const float4* wp = (const float4*)w2m;
        float s = 0.f;
#pragma unroll
        for (int q4 = 0; q4 < 4; q4++) {
            float4 bb = bp[sub * 4 + q4];
            float4 wm = wp[sub * 4 + q4];
            float t0 = dvv * acc[4*q4 + 0] + bb.x; t0 = t0 >= 0.f ? t0 : 0.1f * t0;
            float t1 = dvv * acc[4*q4 + 1] + bb.y; t1 = t1 >= 0.f ? t1 : 0.1f * t1;
            float t2 = dvv * acc[4*q4 + 2] + bb.z; t2 = t2 >= 0.f ? t2 : 0.1f * t2;
            float t3 = dvv * acc[4*q4 + 3] + bb.w; t3 = t3 >= 0.f ? t3 : 0.1f * t3;
            s += t0 * wm.x + t1 * wm.y + t2 * wm.z + t3 * wm.w;
        }
        s += __shfl_xor(s, 1, 64);
        s += __shfl_xor(s, 2, 64);
        s += __shfl_xor(s, 4, 64);
        if (sub == 0) mg[v] = dvv * s;
    }
}

// ---------------- K6: scalar aggregate for conv2 + mean ----------------
__global__ void out_kernel(const int* __restrict__ row, const u16* __restrict__ esrc,
                           const float* __restrict__ mg, const float* __restrict__ dinv,
                           const float* __restrict__ w2m, float* __restrict__ out, int N) {
    int v = blockIdx.x * blockDim.x + threadIdx.x;
    if (v >= N) return;
    float acc = mg[v];
    int jb = row[v], je = row[v + 1];
    int j = jb;
    for (; j + 8 <= je; j += 8) {
        acc += mg[esrc[j]] + mg[esrc[j + 1]] + mg[esrc[j + 2]] + mg[esrc[j + 3]] +
               mg[esrc[j + 4]] + mg[esrc[j + 5]] + mg[esrc[j + 6]] + mg[esrc[j + 7]];
    }
    for (; j < je; j++) acc += mg[esrc[j]];
    out[v] = dinv[v] * acc + w2m[128];
}

extern "C" void kernel_launch(void* const* d_in, const int* in_sizes, int n_in,
                              void* d_out, int out_size, void* d_ws, size_t ws_size,
                              hipStream_t stream) {
    const float* x  = (const float*)d_in[0];
    const int* ei   = (const int*)d_in[1];
    const float* W1 = (const float*)d_in[2];
    const float* b1 = (const float*)d_in[3];
    const float* W2 = (const float*)d_in[4];
    const float* b2 = (const float*)d_in[5];
    float* out = (float*)d_out;

    const int N = N_NODES;
    const int E = in_sizes[1] / 2;
    const int* src = ei;
    const int* dst = ei + E;
    const int CHN = (E + CHUNK - 1) / CHUNK;   // 391
    const int nblocks = (N + 255) / 256;       // 196

    // workspace (4B units). EB is NOT aliased with g16 (sort runs || gemm in K4).
    float*    dinv    = (float*)d_ws;                     // [NPAD]
    int*      row     = (int*)(dinv + NPAD);              // [NPAD+16]
    uint*     B       = (uint*)(row + NPAD + 16);         // [256] (BK+1 used)
    float*    w2m     = (float*)(B + 256);                // [256] ([128]=mean b2)
    float*    mg      = w2m + 256;                        // [NPAD]
    uint*     T       = (uint*)(mg + NPAD);               // [256]
    uint*     counter = T + 256;                          // [16]
    uint*     g16u    = counter + 16;                     // [NPAD*64] (16B aligned)
    u16*      esrc    = (u16*)(g16u + (long)NPAD * 64);   // [E] u16
    uint*     H       = (uint*)(esrc + E);                // [BK*CHN]
    uint*     EB      = H + BK * CHN;                     // [E]

    // K1: histogram chunks + parallel w2m + counter init
    hist_w2m_kernel<<<CHN + 33, 256, 0, stream>>>(dst, H, W2, b2, w2m, counter, E, CHN);
    // K2: per-bucket chunk scan; last block produces B[] and row[N]
    scan_kernel<<<BK, 256, 0, stream>>>(H, T, B, row, counter, CHN, E, N);
    // K3: scatter into bucket regions
    scatter_kernel<<<CHN, 256, 0, stream>>>(src, dst, H, B, EB, E, CHN);
    // K4: bucket sort (196 blocks) || MFMA gemm (782 blocks)
    sortgemm_kernel<<<BK + (N + 63) / 64, 256, 0, stream>>>(EB, B, row, dinv, esrc,
                                                            x, W1, g16u, N, N);
    // K5: gather + lrelu + dot -> mg
    gather_node_kernel<<<(N + 3) / 4, 256, 0, stream>>>(row, esrc, g16u, dinv, b1, w2m, mg, N);
    // K6: scalar aggregate + mean -> out
    out_kernel<<<nblocks, 256, 0, stream>>>(row, esrc, mg, dinv, w2m, out, N);
}